// Round 4
// baseline (337.510 us; speedup 1.0000x reference)
//
#include <hip/hip_runtime.h>
#include <stdint.h>

#define DIM   128
#define KCOLS 65536
#define BB    1024
#define LL    512
#define PSZ   8388608
#define INV_T (1.0f / 0.09f)
#define MOM   0.7f

// output layout (float32 elements, concatenated in return order)
#define OUT_LOGITS 0
#define OUT_LABELS (BB * LL)                    // 524288
#define OUT_QUEUE  (BB * LL + BB)               // 525312
#define OUT_PARAMK (BB * LL + BB + DIM * KCOLS) // 8913920

// ws layout (bytes)
#define WS_QT   0                               // bf16 queueT [KCOLS][DIM] = 16 MiB
#define WS_QN16 (KCOLS * DIM * 2)               // bf16 normalized q [BB][DIM] = 256 KiB
#define WS_KN   (WS_QN16 + BB * DIM * 2)        // f32 normalized keys [BB][DIM] = 512 KiB
#define WS_HIST (WS_KN + BB * DIM * 4)          // u32 hist[2048]
#define WS_OFF  (WS_HIST + 2048 * 4)            // u32 offsets[2049]
#define WS_CUR  (WS_OFF + 2064 * 4)             // u32 cursor[2048]
#define WS_ENT  (WS_CUR + 2048 * 4)             // u32 entries[524288] = 2 MiB

typedef short short8 __attribute__((ext_vector_type(8)));
typedef float floatx4 __attribute__((ext_vector_type(4)));

__device__ inline unsigned short f32_to_bf16(float f) {
    uint32_t u = __float_as_uint(f);
    uint32_t r = (u + 0x7fffu + ((u >> 16) & 1u)) >> 16;
    return (unsigned short)r;
}

// one wave per row; rows 0..BB-1 = q -> qn16 (normalized bf16), BB..2BB-1 = keys -> kn (f32)
__global__ void norm_kernel(const float* __restrict__ q,
                            const float* __restrict__ keys,
                            uint32_t* __restrict__ qn16, float* __restrict__ kn) {
    int w    = threadIdx.x >> 6;
    int lane = threadIdx.x & 63;
    int row  = blockIdx.x * 4 + w;   // 0..2047
    if (row < BB) {
        float2 v = *(const float2*)&q[row * DIM + lane * 2];
        float s  = v.x * v.x + v.y * v.y;
#pragma unroll
        for (int m = 32; m >= 1; m >>= 1) s += __shfl_xor(s, m, 64);
        float inv = 1.0f / sqrtf(s);
        uint32_t pk = (uint32_t)f32_to_bf16(v.x * inv) |
                      ((uint32_t)f32_to_bf16(v.y * inv) << 16);
        qn16[row * 64 + lane] = pk;
    } else {
        int r = row - BB;
        float2 v = *(const float2*)&keys[r * DIM + lane * 2];
        float s  = v.x * v.x + v.y * v.y;
#pragma unroll
        for (int m = 32; m >= 1; m >>= 1) s += __shfl_xor(s, m, 64);
        float inv = 1.0f / sqrtf(s);
        float2 o  = {v.x * inv, v.y * inv};
        *(float2*)&kn[r * DIM + lane * 2] = o;
    }
}

// new_param_k = MOM*param_k + (1-MOM)*param_q ; also writes labels (zeros)
__global__ void param_kernel(const float* __restrict__ pq,
                             const float* __restrict__ pk,
                             float* __restrict__ out) {
    int gid  = blockIdx.x * blockDim.x + threadIdx.x;
    float4 a = ((const float4*)pq)[gid];
    float4 b = ((const float4*)pk)[gid];
    float4 r;
    r.x = b.x * MOM + a.x * (1.0f - MOM);
    r.y = b.y * MOM + a.y * (1.0f - MOM);
    r.z = b.z * MOM + a.z * (1.0f - MOM);
    r.w = b.w * MOM + a.w * (1.0f - MOM);
    ((float4*)(out + OUT_PARAMK))[gid] = r;
    if (gid < BB) out[OUT_LABELS + gid] = 0.0f;
}

// Fused: read queue once (float4-coalesced); write new_queue (float4) AND
// bf16 transposed qt[KCOLS][DIM] (uint4 rows), via LDS tile.
__global__ void queue_fused_kernel(const float* __restrict__ queue,
                                   const float* __restrict__ kn,
                                   const int* __restrict__ ptr_p,
                                   float* __restrict__ outq,
                                   unsigned short* __restrict__ qt) {
    __shared__ float tile[64][DIM + 1];  // [k][d], 33 KB
    int k0 = blockIdx.x * 64;
    int t  = threadIdx.x;
    int ptr   = ptr_p[0];
    int start = min(max(ptr, 0), KCOLS - BB);  // dynamic_update_slice clamp

    int lane16 = t & 15;
    int hi     = t >> 4;       // 0..15
    int kq     = lane16 * 4;   // column offset within tile, step 4
#pragma unroll
    for (int p = 0; p < 8; ++p) {
        int d = p * 16 + hi;
        float4 v = *(const float4*)&queue[(size_t)d * KCOLS + k0 + kq];
        float vv[4] = {v.x, v.y, v.z, v.w};
#pragma unroll
        for (int j = 0; j < 4; ++j) {
            tile[kq + j][d] = vv[j];           // original value for qt
            int col = k0 + kq + j;
            if (col >= start && col < start + BB)
                vv[j] = kn[(size_t)(col - start) * DIM + d];
        }
        float4 w = {vv[0], vv[1], vv[2], vv[3]};
        *(float4*)&outq[(size_t)d * KCOLS + k0 + kq] = w;
    }
    __syncthreads();
    int d0 = lane16 * 8;
#pragma unroll
    for (int ki = 0; ki < 4; ++ki) {
        int kl = hi + ki * 16;  // 0..63
        float f[8];
#pragma unroll
        for (int j = 0; j < 8; ++j) f[j] = tile[kl][d0 + j];
        uint4 o;
        o.x = (uint32_t)f32_to_bf16(f[0]) | ((uint32_t)f32_to_bf16(f[1]) << 16);
        o.y = (uint32_t)f32_to_bf16(f[2]) | ((uint32_t)f32_to_bf16(f[3]) << 16);
        o.z = (uint32_t)f32_to_bf16(f[4]) | ((uint32_t)f32_to_bf16(f[5]) << 16);
        o.w = (uint32_t)f32_to_bf16(f[6]) | ((uint32_t)f32_to_bf16(f[7]) << 16);
        *(uint4*)&qt[(size_t)(k0 + kl) * DIM + d0] = o;
    }
}

// ---- binning: tile = (b>>7)*256 + (idx>>8), 2048 tiles (8 btile x 256 ktile)
__global__ void hist_kernel(const int* __restrict__ sidx, uint32_t* __restrict__ hist) {
    int i   = blockIdx.x * 256 + threadIdx.x;  // < 524288
    int idx = sidx[i];
    int b   = i >> 9;
    atomicAdd(&hist[(b >> 7) * 256 + (idx >> 8)], 1u);
}

// Blelloch exclusive scan of 2048 bins, one block of 1024 threads
__global__ void scan_kernel(const uint32_t* __restrict__ hist,
                            uint32_t* __restrict__ offsets,
                            uint32_t* __restrict__ cursor) {
    __shared__ uint32_t s[2048];
    int t = threadIdx.x;
    s[t] = hist[t]; s[t + 1024] = hist[t + 1024];
    __syncthreads();
    int offset = 1;
    for (int n = 1024; n > 0; n >>= 1) {
        if (t < n) {
            int ai = offset * (2 * t + 1) - 1, bi = offset * (2 * t + 2) - 1;
            s[bi] += s[ai];
        }
        offset <<= 1;
        __syncthreads();
    }
    if (t == 0) { offsets[2048] = s[2047]; s[2047] = 0; }
    __syncthreads();
    for (int n = 1; n < 2048; n <<= 1) {
        offset >>= 1;
        if (t < n) {
            int ai = offset * (2 * t + 1) - 1, bi = offset * (2 * t + 2) - 1;
            uint32_t tmp = s[ai]; s[ai] = s[bi]; s[bi] += tmp;
        }
        __syncthreads();
    }
    offsets[t] = s[t]; offsets[t + 1024] = s[t + 1024];
    cursor[t]  = s[t]; cursor[t + 1024]  = s[t + 1024];
}

__global__ void scatter_kernel(const int* __restrict__ sidx,
                               uint32_t* __restrict__ cursor,
                               uint32_t* __restrict__ entries) {
    int i   = blockIdx.x * 256 + threadIdx.x;
    int idx = sidx[i];
    int b   = i >> 9, l = i & 511;
    int tile = (b >> 7) * 256 + (idx >> 8);
    uint32_t pos = atomicAdd(&cursor[tile], 1u);
    entries[pos] = ((uint32_t)l << 15) | ((uint32_t)(b & 127) << 8) | (uint32_t)(idx & 255);
}

// Dense GEMM C[b,k] = qn16 . qt^T over 128x256 tiles; epilogue scatters only
// the sampled entries. Block = 4 waves; wave w owns k-slice [w*64, w*64+64).
// LDS: A-tile 32KB (chunks 0..2048) + B-tile 64KB (chunks 2048..6144), XOR-16B
// swizzled (2-way bank conflicts only). Epilogue reuses LDS as f32 C[128][129].
__global__ void __launch_bounds__(256, 1)
gemm_logits_kernel(const unsigned short* __restrict__ qn16,
                   const unsigned short* __restrict__ qt,
                   const uint32_t* __restrict__ entries,
                   const uint32_t* __restrict__ offsets,
                   float* __restrict__ out_logits) {
    __shared__ uint4 smem[6144];  // 96 KB
    int bx    = blockIdx.x;
    int ktile = bx >> 3, btile = bx & 7;   // k-major: 8 b-tiles share a k-tile
    int b0 = btile * 128, k0 = ktile * 256;
    int tid  = threadIdx.x;
    int w    = tid >> 6, lane = tid & 63;
    int quad = lane >> 4, l15 = lane & 15;

    // stage A (32KB linear) and B (64KB linear), loads first then LDS writes
    const uint4* gA = (const uint4*)(qn16 + (size_t)b0 * DIM);
    const uint4* gB = (const uint4*)(qt + (size_t)k0 * DIM);
    uint4 va[8], vb[16];
#pragma unroll
    for (int r = 0; r < 8; ++r) va[r] = gA[r * 256 + tid];
#pragma unroll
    for (int r = 0; r < 16; ++r) vb[r] = gB[r * 256 + tid];
#pragma unroll
    for (int r = 0; r < 8; ++r) {
        int i = r * 256 + tid, row = i >> 4, j = i & 15;
        smem[row * 16 + (j ^ (row & 15))] = va[r];
    }
#pragma unroll
    for (int r = 0; r < 16; ++r) {
        int i = r * 256 + tid, row = i >> 4, j = i & 15;
        smem[2048 + row * 16 + (j ^ (row & 15))] = vb[r];
    }
    __syncthreads();

    // B fragments for this wave's 64 k-columns: nt 0..3, k-step s 0..3
    short8 bf[4][4];
#pragma unroll
    for (int nt = 0; nt < 4; ++nt) {
        int krow = w * 64 + nt * 16 + l15;
#pragma unroll
        for (int s = 0; s < 4; ++s)
            bf[nt][s] = *(const short8*)&smem[2048 + krow * 16 + ((s * 4 + quad) ^ (krow & 15))];
    }
    floatx4 acc[8][4];
#pragma unroll
    for (int mt = 0; mt < 8; ++mt)
#pragma unroll
        for (int nt = 0; nt < 4; ++nt) acc[mt][nt] = (floatx4)(0.0f);

#pragma unroll
    for (int mt = 0; mt < 8; ++mt) {
        int arow = mt * 16 + l15;
        short8 af[4];
#pragma unroll
        for (int s = 0; s < 4; ++s)
            af[s] = *(const short8*)&smem[arow * 16 + ((s * 4 + quad) ^ (arow & 15))];
#pragma unroll
        for (int nt = 0; nt < 4; ++nt)
#pragma unroll
            for (int s = 0; s < 4; ++s)
                acc[mt][nt] = __builtin_amdgcn_mfma_f32_16x16x32_bf16(
                    af[s], bf[nt][s], acc[mt][nt], 0, 0, 0);
    }

    // epilogue: two k-halves of 128; C staged f32 in LDS with stride 129
    float* cLds = (float*)smem;
    int tile = btile * 256 + ktile;
    uint32_t off = offsets[tile], end = offsets[tile + 1];
#pragma unroll
    for (int h = 0; h < 2; ++h) {
        __syncthreads();
        if ((w >> 1) == h) {  // waves 0,1 own k 0..127; waves 2,3 own 128..255
#pragma unroll
            for (int mt = 0; mt < 8; ++mt)
#pragma unroll
                for (int nt = 0; nt < 4; ++nt) {
                    int kloc = (w * 64 + nt * 16 + l15) & 127;
#pragma unroll
                    for (int rg = 0; rg < 4; ++rg) {
                        int brel = mt * 16 + quad * 4 + rg;
                        cLds[brel * 129 + kloc] = acc[mt][nt][rg];
                    }
                }
        }
        __syncthreads();
        for (uint32_t i = off + tid; i < end; i += 256) {
            uint32_t e = entries[i];
            int krel = e & 255;
            if ((krel >> 7) != h) continue;
            int brel = (e >> 8) & 127;
            int l    = (int)(e >> 15);
            out_logits[(size_t)(b0 + brel) * LL + l] =
                cLds[brel * 129 + (krel & 127)] * INV_T;
        }
    }
}

extern "C" void kernel_launch(void* const* d_in, const int* in_sizes, int n_in,
                              void* d_out, int out_size, void* d_ws, size_t ws_size,
                              hipStream_t stream) {
    const float* q     = (const float*)d_in[0];
    const float* queue = (const float*)d_in[1];
    const float* keys  = (const float*)d_in[2];
    const float* pq    = (const float*)d_in[3];
    const float* pk    = (const float*)d_in[4];
    const int*   sidx  = (const int*)d_in[5];
    const int*   ptr_p = (const int*)d_in[6];
    float* out = (float*)d_out;

    unsigned short* ws_qt  = (unsigned short*)((char*)d_ws + WS_QT);
    uint32_t* ws_qn16      = (uint32_t*)((char*)d_ws + WS_QN16);
    float* ws_kn           = (float*)((char*)d_ws + WS_KN);
    uint32_t* ws_hist      = (uint32_t*)((char*)d_ws + WS_HIST);
    uint32_t* ws_off       = (uint32_t*)((char*)d_ws + WS_OFF);
    uint32_t* ws_cur       = (uint32_t*)((char*)d_ws + WS_CUR);
    uint32_t* ws_ent       = (uint32_t*)((char*)d_ws + WS_ENT);

    hipMemsetAsync(ws_hist, 0, 2048 * 4, stream);
    // 1) row norms: qn (bf16), kn (f32)
    norm_kernel<<<512, 256, 0, stream>>>(q, keys, ws_qn16, ws_kn);
    // 2) fused queue copy/overwrite + bf16 transpose
    queue_fused_kernel<<<KCOLS / 64, 256, 0, stream>>>(queue, ws_kn, ptr_p,
                                                       out + OUT_QUEUE, ws_qt);
    // 3) binning CSR: hist -> scan -> scatter
    hist_kernel<<<2048, 256, 0, stream>>>(sidx, ws_hist);
    scan_kernel<<<1, 1024, 0, stream>>>(ws_hist, ws_off, ws_cur);
    scatter_kernel<<<2048, 256, 0, stream>>>(sidx, ws_cur, ws_ent);
    // 4) momentum param update + labels
    param_kernel<<<PSZ / 4 / 256, 256, 0, stream>>>(pq, pk, out);
    // 5) dense MFMA GEMM + entry scatter epilogue
    gemm_logits_kernel<<<2048, 256, 0, stream>>>((const unsigned short*)ws_qn16,
                                                 ws_qt, ws_ent, ws_off,
                                                 out + OUT_LOGITS);
}

// Round 5
// 231.597 us; speedup vs baseline: 1.4573x; 1.4573x over previous
//
#include <hip/hip_runtime.h>
#include <stdint.h>

#define DIM   128
#define KCOLS 65536
#define BB    1024
#define LL    512
#define PSZ   8388608
#define INV_T (1.0f / 0.09f)
#define MOM   0.7f

// output layout (float32 elements, concatenated in return order)
#define OUT_LOGITS 0
#define OUT_LABELS (BB * LL)                    // 524288
#define OUT_QUEUE  (BB * LL + BB)               // 525312
#define OUT_PARAMK (BB * LL + BB + DIM * KCOLS) // 8913920

// ws layout (bytes)
#define WS_QT    0                              // bf16 queueT [KCOLS][DIM] = 16 MiB
#define WS_QN16  (KCOLS * DIM * 2)              // bf16 normalized q [BB][DIM]
#define WS_KN    (WS_QN16 + BB * DIM * 2)       // f32 normalized keys
#define WS_PART  (WS_KN + BB * DIM * 4)         // u32 partial[64][256]
#define WS_CBASE (WS_PART + 64 * 256 * 4)       // u32 chunkbase[64][256]
#define WS_OFF   (WS_CBASE + 64 * 256 * 4)      // u32 offsets[2049]
#define WS_ENT   (WS_OFF + 16384)               // u32 entries[524288] = 2 MiB

typedef short short8 __attribute__((ext_vector_type(8)));
typedef float floatx4 __attribute__((ext_vector_type(4)));

__device__ inline unsigned short f32_to_bf16(float f) {
    uint32_t u = __float_as_uint(f);
    uint32_t r = (u + 0x7fffu + ((u >> 16) & 1u)) >> 16;
    return (unsigned short)r;
}

// one wave per row; rows 0..BB-1 = q -> qn16 (normalized bf16), BB..2BB-1 = keys -> kn (f32)
__global__ void norm_kernel(const float* __restrict__ q,
                            const float* __restrict__ keys,
                            uint32_t* __restrict__ qn16, float* __restrict__ kn) {
    int w    = threadIdx.x >> 6;
    int lane = threadIdx.x & 63;
    int row  = blockIdx.x * 4 + w;   // 0..2047
    if (row < BB) {
        float2 v = *(const float2*)&q[row * DIM + lane * 2];
        float s  = v.x * v.x + v.y * v.y;
#pragma unroll
        for (int m = 32; m >= 1; m >>= 1) s += __shfl_xor(s, m, 64);
        float inv = 1.0f / sqrtf(s);
        uint32_t pk = (uint32_t)f32_to_bf16(v.x * inv) |
                      ((uint32_t)f32_to_bf16(v.y * inv) << 16);
        qn16[row * 64 + lane] = pk;
    } else {
        int r = row - BB;
        float2 v = *(const float2*)&keys[r * DIM + lane * 2];
        float s  = v.x * v.x + v.y * v.y;
#pragma unroll
        for (int m = 32; m >= 1; m >>= 1) s += __shfl_xor(s, m, 64);
        float inv = 1.0f / sqrtf(s);
        float2 o  = {v.x * inv, v.y * inv};
        *(float2*)&kn[r * DIM + lane * 2] = o;
    }
}

// new_param_k = MOM*param_k + (1-MOM)*param_q ; also writes labels (zeros)
__global__ void param_kernel(const float* __restrict__ pq,
                             const float* __restrict__ pk,
                             float* __restrict__ out) {
    int gid  = blockIdx.x * blockDim.x + threadIdx.x;
    float4 a = ((const float4*)pq)[gid];
    float4 b = ((const float4*)pk)[gid];
    float4 r;
    r.x = b.x * MOM + a.x * (1.0f - MOM);
    r.y = b.y * MOM + a.y * (1.0f - MOM);
    r.z = b.z * MOM + a.z * (1.0f - MOM);
    r.w = b.w * MOM + a.w * (1.0f - MOM);
    ((float4*)(out + OUT_PARAMK))[gid] = r;
    if (gid < BB) out[OUT_LABELS + gid] = 0.0f;
}

// Fused: read queue once (float4-coalesced); write new_queue (float4) AND
// bf16 transposed qt[KCOLS][DIM] (uint4 rows), via LDS tile.
__global__ void queue_fused_kernel(const float* __restrict__ queue,
                                   const float* __restrict__ kn,
                                   const int* __restrict__ ptr_p,
                                   float* __restrict__ outq,
                                   unsigned short* __restrict__ qt) {
    __shared__ float tile[64][DIM + 1];  // [k][d], 33 KB
    int k0 = blockIdx.x * 64;
    int t  = threadIdx.x;
    int ptr   = ptr_p[0];
    int start = min(max(ptr, 0), KCOLS - BB);  // dynamic_update_slice clamp

    int lane16 = t & 15;
    int hi     = t >> 4;       // 0..15
    int kq     = lane16 * 4;   // column offset within tile, step 4
#pragma unroll
    for (int p = 0; p < 8; ++p) {
        int d = p * 16 + hi;
        float4 v = *(const float4*)&queue[(size_t)d * KCOLS + k0 + kq];
        float vv[4] = {v.x, v.y, v.z, v.w};
#pragma unroll
        for (int j = 0; j < 4; ++j) {
            tile[kq + j][d] = vv[j];           // original value for qt
            int col = k0 + kq + j;
            if (col >= start && col < start + BB)
                vv[j] = kn[(size_t)(col - start) * DIM + d];
        }
        float4 w = {vv[0], vv[1], vv[2], vv[3]};
        *(float4*)&outq[(size_t)d * KCOLS + k0 + kq] = w;
    }
    __syncthreads();
    int d0 = lane16 * 8;
#pragma unroll
    for (int ki = 0; ki < 4; ++ki) {
        int kl = hi + ki * 16;  // 0..63
        float f[8];
#pragma unroll
        for (int j = 0; j < 8; ++j) f[j] = tile[kl][d0 + j];
        uint4 o;
        o.x = (uint32_t)f32_to_bf16(f[0]) | ((uint32_t)f32_to_bf16(f[1]) << 16);
        o.y = (uint32_t)f32_to_bf16(f[2]) | ((uint32_t)f32_to_bf16(f[3]) << 16);
        o.z = (uint32_t)f32_to_bf16(f[4]) | ((uint32_t)f32_to_bf16(f[5]) << 16);
        o.w = (uint32_t)f32_to_bf16(f[6]) | ((uint32_t)f32_to_bf16(f[7]) << 16);
        *(uint4*)&qt[(size_t)(k0 + kl) * DIM + d0] = o;
    }
}

// ---- CSR build, btile-local (no global atomics) --------------------------
// Partition: 64 chunks of 8192 consecutive sidx entries; chunk c belongs to
// btile c>>3. Bin = idx>>8 (256 ktile bins). Each btile has EXACTLY 65536
// entries, so its base in entries[] is btile*65536 statically.

// per-chunk LDS histogram -> partial[c][bin]
__global__ void hist2_kernel(const int* __restrict__ sidx,
                             uint32_t* __restrict__ partial) {
    __shared__ uint32_t hist[256];
    int c = blockIdx.x, t = threadIdx.x;
    if (t < 256) hist[t] = 0;
    __syncthreads();
#pragma unroll
    for (int j = 0; j < 8; ++j) {
        int idx = sidx[c * 8192 + j * 1024 + t];
        atomicAdd(&hist[idx >> 8], 1u);
    }
    __syncthreads();
    if (t < 256) partial[c * 256 + t] = hist[t];
}

// per-btile exclusive scan over [ktile][chunk] (2048 vals) ->
// chunkbase[c][ktile] and offsets[btile*256+ktile]
__global__ void scan2_kernel(const uint32_t* __restrict__ partial,
                             uint32_t* __restrict__ chunkbase,
                             uint32_t* __restrict__ offsets) {
    __shared__ uint32_t s[2048];
    int bt = blockIdx.x, t = threadIdx.x;
    uint32_t base = (uint32_t)bt * 65536u;
#pragma unroll
    for (int h = 0; h < 2; ++h) {
        int f = t + h * 1024;                       // f = ktile*8 + chunk
        s[f] = partial[(bt * 8 + (f & 7)) * 256 + (f >> 3)];
    }
    __syncthreads();
    int offset = 1;
    for (int n = 1024; n > 0; n >>= 1) {
        if (t < n) {
            int ai = offset * (2 * t + 1) - 1, bi = offset * (2 * t + 2) - 1;
            s[bi] += s[ai];
        }
        offset <<= 1;
        __syncthreads();
    }
    if (t == 0) s[2047] = 0;
    __syncthreads();
    for (int n = 1; n < 2048; n <<= 1) {
        offset >>= 1;
        if (t < n) {
            int ai = offset * (2 * t + 1) - 1, bi = offset * (2 * t + 2) - 1;
            uint32_t tmp = s[ai]; s[ai] = s[bi]; s[bi] += tmp;
        }
        __syncthreads();
    }
#pragma unroll
    for (int h = 0; h < 2; ++h) {
        int f = t + h * 1024;
        chunkbase[(bt * 8 + (f & 7)) * 256 + (f >> 3)] = base + s[f];
        if ((f & 7) == 0) offsets[bt * 256 + (f >> 3)] = base + s[f];
    }
    if (bt == 0 && t == 0) offsets[2048] = BB * LL;
}

// scatter with per-chunk exclusive ranges; only LDS return-atomics
__global__ void scatter2_kernel(const int* __restrict__ sidx,
                                const uint32_t* __restrict__ chunkbase,
                                uint32_t* __restrict__ entries) {
    __shared__ uint32_t cur[256];
    int c = blockIdx.x, t = threadIdx.x;
    if (t < 256) cur[t] = chunkbase[c * 256 + t];
    __syncthreads();
#pragma unroll
    for (int j = 0; j < 8; ++j) {
        int i   = c * 8192 + j * 1024 + t;
        int idx = sidx[i];
        int b   = i >> 9, l = i & 511;
        uint32_t pos = atomicAdd(&cur[idx >> 8], 1u);
        entries[pos] = ((uint32_t)l << 15) | ((uint32_t)(b & 127) << 8) |
                       (uint32_t)(idx & 255);
    }
}

// Dense GEMM C[b,k] = qn16 . qt^T over 128x256 tiles; epilogue scatters only
// the sampled entries. Block = 4 waves; wave w owns k-slice [w*64, w*64+64).
__global__ void __launch_bounds__(256, 1)
gemm_logits_kernel(const unsigned short* __restrict__ qn16,
                   const unsigned short* __restrict__ qt,
                   const uint32_t* __restrict__ entries,
                   const uint32_t* __restrict__ offsets,
                   float* __restrict__ out_logits) {
    __shared__ uint4 smem[6144];  // 96 KB
    int bx    = blockIdx.x;
    int ktile = bx >> 3, btile = bx & 7;   // k-major: 8 b-tiles share a k-tile
    int b0 = btile * 128, k0 = ktile * 256;
    int tid  = threadIdx.x;
    int w    = tid >> 6, lane = tid & 63;
    int quad = lane >> 4, l15 = lane & 15;

    const uint4* gA = (const uint4*)(qn16 + (size_t)b0 * DIM);
    const uint4* gB = (const uint4*)(qt + (size_t)k0 * DIM);
    uint4 va[8], vb[16];
#pragma unroll
    for (int r = 0; r < 8; ++r) va[r] = gA[r * 256 + tid];
#pragma unroll
    for (int r = 0; r < 16; ++r) vb[r] = gB[r * 256 + tid];
#pragma unroll
    for (int r = 0; r < 8; ++r) {
        int i = r * 256 + tid, row = i >> 4, j = i & 15;
        smem[row * 16 + (j ^ (row & 15))] = va[r];
    }
#pragma unroll
    for (int r = 0; r < 16; ++r) {
        int i = r * 256 + tid, row = i >> 4, j = i & 15;
        smem[2048 + row * 16 + (j ^ (row & 15))] = vb[r];
    }
    __syncthreads();

    short8 bf[4][4];
#pragma unroll
    for (int nt = 0; nt < 4; ++nt) {
        int krow = w * 64 + nt * 16 + l15;
#pragma unroll
        for (int s = 0; s < 4; ++s)
            bf[nt][s] = *(const short8*)&smem[2048 + krow * 16 + ((s * 4 + quad) ^ (krow & 15))];
    }
    floatx4 acc[8][4];
#pragma unroll
    for (int mt = 0; mt < 8; ++mt)
#pragma unroll
        for (int nt = 0; nt < 4; ++nt) acc[mt][nt] = (floatx4)(0.0f);

#pragma unroll
    for (int mt = 0; mt < 8; ++mt) {
        int arow = mt * 16 + l15;
        short8 af[4];
#pragma unroll
        for (int s = 0; s < 4; ++s)
            af[s] = *(const short8*)&smem[arow * 16 + ((s * 4 + quad) ^ (arow & 15))];
#pragma unroll
        for (int nt = 0; nt < 4; ++nt)
#pragma unroll
            for (int s = 0; s < 4; ++s)
                acc[mt][nt] = __builtin_amdgcn_mfma_f32_16x16x32_bf16(
                    af[s], bf[nt][s], acc[mt][nt], 0, 0, 0);
    }

    // epilogue: two k-halves of 128; C staged f32 in LDS with stride 129
    float* cLds = (float*)smem;
    int tile = btile * 256 + ktile;
    uint32_t off = offsets[tile], end = offsets[tile + 1];
#pragma unroll
    for (int h = 0; h < 2; ++h) {
        __syncthreads();
        if ((w >> 1) == h) {  // waves 0,1 own k 0..127; waves 2,3 own 128..255
#pragma unroll
            for (int mt = 0; mt < 8; ++mt)
#pragma unroll
                for (int nt = 0; nt < 4; ++nt) {
                    int kloc = (w * 64 + nt * 16 + l15) & 127;
#pragma unroll
                    for (int rg = 0; rg < 4; ++rg) {
                        int brel = mt * 16 + quad * 4 + rg;
                        cLds[brel * 129 + kloc] = acc[mt][nt][rg];
                    }
                }
        }
        __syncthreads();
        for (uint32_t i = off + tid; i < end; i += 256) {
            uint32_t e = entries[i];
            int krel = e & 255;
            if ((krel >> 7) != h) continue;
            int brel = (e >> 8) & 127;
            int l    = (int)(e >> 15);
            out_logits[(size_t)(b0 + brel) * LL + l] =
                cLds[brel * 129 + (krel & 127)] * INV_T;
        }
    }
}

extern "C" void kernel_launch(void* const* d_in, const int* in_sizes, int n_in,
                              void* d_out, int out_size, void* d_ws, size_t ws_size,
                              hipStream_t stream) {
    const float* q     = (const float*)d_in[0];
    const float* queue = (const float*)d_in[1];
    const float* keys  = (const float*)d_in[2];
    const float* pq    = (const float*)d_in[3];
    const float* pk    = (const float*)d_in[4];
    const int*   sidx  = (const int*)d_in[5];
    const int*   ptr_p = (const int*)d_in[6];
    float* out = (float*)d_out;

    unsigned short* ws_qt = (unsigned short*)((char*)d_ws + WS_QT);
    uint32_t* ws_qn16     = (uint32_t*)((char*)d_ws + WS_QN16);
    float* ws_kn          = (float*)((char*)d_ws + WS_KN);
    uint32_t* ws_part     = (uint32_t*)((char*)d_ws + WS_PART);
    uint32_t* ws_cbase    = (uint32_t*)((char*)d_ws + WS_CBASE);
    uint32_t* ws_off      = (uint32_t*)((char*)d_ws + WS_OFF);
    uint32_t* ws_ent      = (uint32_t*)((char*)d_ws + WS_ENT);

    // 1) row norms: qn (bf16), kn (f32)
    norm_kernel<<<512, 256, 0, stream>>>(q, keys, ws_qn16, ws_kn);
    // 2) fused queue copy/overwrite + bf16 transpose
    queue_fused_kernel<<<KCOLS / 64, 256, 0, stream>>>(queue, ws_kn, ptr_p,
                                                       out + OUT_QUEUE, ws_qt);
    // 3) CSR: per-chunk hist -> per-btile scan -> local scatter
    hist2_kernel<<<64, 1024, 0, stream>>>(sidx, ws_part);
    scan2_kernel<<<8, 1024, 0, stream>>>(ws_part, ws_cbase, ws_off);
    scatter2_kernel<<<64, 1024, 0, stream>>>(sidx, ws_cbase, ws_ent);
    // 4) momentum param update + labels
    param_kernel<<<PSZ / 4 / 256, 256, 0, stream>>>(pq, pk, out);
    // 5) dense MFMA GEMM + entry scatter epilogue
    gemm_logits_kernel<<<2048, 256, 0, stream>>>((const unsigned short*)ws_qn16,
                                                 ws_qt, ws_ent, ws_off,
                                                 out + OUT_LOGITS);
}